// Round 1
// baseline (896.935 us; speedup 1.0000x reference)
//
#include <hip/hip_runtime.h>
#include <hip/hip_bf16.h>

#define B_ 16
#define T_ 12
#define N_ 512
#define D_ 64
#define EDS_ 32
#define HS_ 16
#define HT_ 32
#define TT_ 192
#define BT_ (B_*T_)

__device__ __forceinline__ float warp_sum64(float v) {
    #pragma unroll
    for (int off = 32; off > 0; off >>= 1) v += __shfl_xor(v, off);
    return v;
}

__device__ __forceinline__ float squash_factor(float sq) {
    return (sq / (1.f + sq)) / (sqrtf(sq) + 1e-8f);
}

__device__ __forceinline__ float lrelu(float v) {
    return (v >= 0.f) ? v : 0.01f * v;
}

// -------- Kernel 1: Pc = squash(x @ W_p + b_p) --------------------------
// grid = B*T*N/4 blocks, 256 threads; one wave per row of 64.
__global__ __launch_bounds__(256) void k_pc(const float* __restrict__ x,
        const float* __restrict__ Wp, const float* __restrict__ bp,
        float* __restrict__ Pc) {
    __shared__ float Ws[64][64];
    __shared__ float xs[4][64];
    int tid = threadIdx.x;
    for (int i = tid; i < 4096; i += 256) Ws[i >> 6][i & 63] = Wp[i];
    int r = tid >> 6;
    int d = tid & 63;
    long row = (long)blockIdx.x * 4 + r;
    xs[r][d] = x[row * 64 + d];
    __syncthreads();
    float acc = bp[d];
    #pragma unroll
    for (int k = 0; k < 64; ++k) acc += xs[r][k] * Ws[k][d];
    float sq = warp_sum64(acc * acc);
    Pc[row * 64 + d] = acc * squash_factor(sq);
}

// -------- Kernel 2: dadj[b,t,h,n] = sum_d teb[b,t,d]*adj[d,h,n] --------
__global__ __launch_bounds__(256) void k_dadj(const float* __restrict__ teb,
        const float* __restrict__ adj, float* __restrict__ dadj) {
    int bt = blockIdx.x;
    __shared__ float ts[32];
    int tid = threadIdx.x;
    if (tid < 32) ts[tid] = teb[bt * 32 + tid];
    __syncthreads();
    for (int idx = tid; idx < HS_ * N_; idx += 256) {
        int h = idx >> 9, n = idx & 511;
        float acc = 0.f;
        #pragma unroll
        for (int dd = 0; dd < 32; ++dd) acc += ts[dd] * adj[(dd * 16 + h) * 512 + n];
        dadj[(bt * 16 + h) * 512 + n] = acc;
    }
}

// -------- Kernel 3: test1 = softmax(dadj,h) @ Pc ; sqt = squash(test1) --
__global__ __launch_bounds__(256) void k_test1(const float* __restrict__ dadj,
        const float* __restrict__ Pc, float* __restrict__ sqt) {
    int bt = blockIdx.x;
    __shared__ float Pcs[32][65];
    __shared__ float cs[16][33];
    int tid = threadIdx.x;
    int d = tid & 63, hq = tid >> 6;
    float acc[4] = {0.f, 0.f, 0.f, 0.f};
    const float* dbase = dadj + bt * (HS_ * N_);
    const float* pbase = Pc + (long)bt * N_ * D_;
    for (int n0 = 0; n0 < 512; n0 += 32) {
        for (int i = tid; i < 512; i += 256) {
            int h = i >> 5, nl = i & 31;
            cs[h][nl] = dbase[h * 512 + n0 + nl];
        }
        for (int i = tid; i < 2048; i += 256) {
            int nl = i >> 6, dd = i & 63;
            Pcs[nl][dd] = pbase[(n0 + nl) * 64 + dd];
        }
        __syncthreads();
        if (tid < 32) {
            float vv[16];
            float m = -1e30f;
            #pragma unroll
            for (int h = 0; h < 16; ++h) { vv[h] = cs[h][tid]; m = fmaxf(m, vv[h]); }
            float ssum = 0.f;
            #pragma unroll
            for (int h = 0; h < 16; ++h) { vv[h] = __expf(vv[h] - m); ssum += vv[h]; }
            float inv = 1.f / ssum;
            #pragma unroll
            for (int h = 0; h < 16; ++h) cs[h][tid] = vv[h] * inv;
        }
        __syncthreads();
        for (int nl = 0; nl < 32; ++nl) {
            float p = Pcs[nl][d];
            #pragma unroll
            for (int j = 0; j < 4; ++j) acc[j] += cs[hq + 4 * j][nl] * p;
        }
        __syncthreads();
    }
    #pragma unroll
    for (int j = 0; j < 4; ++j) {
        float sq = warp_sum64(acc[j] * acc[j]);
        sqt[(bt * 16 + hq + 4 * j) * 64 + d] = acc[j] * squash_factor(sq);
    }
}

// -------- Kernel 4: dynamic routing (3 iters) + final c, s -------------
__global__ __launch_bounds__(256) void k_route(const float* __restrict__ dadj,
        const float* __restrict__ Pc, const float* __restrict__ sqt,
        float* __restrict__ c_out, float* __restrict__ s_out) {
    int bt = blockIdx.x;
    __shared__ float blog[16][512];
    __shared__ float Pcs[32][65];
    __shared__ float cs[16][33];
    __shared__ float sq1[16][64];
    __shared__ float sv[16][64];
    int tid = threadIdx.x;
    int d = tid & 63, hq = tid >> 6;
    const float* dbase = dadj + bt * (HS_ * N_);
    const float* pbase = Pc + (long)bt * N_ * D_;
    for (int i = tid; i < 8192; i += 256) blog[i >> 9][i & 511] = 0.f;
    for (int i = tid; i < 1024; i += 256) sq1[i >> 6][i & 63] = sqt[bt * 1024 + i];
    __syncthreads();
    for (int it = 0; it < 4; ++it) {
        const bool fin = (it == 3);
        float acc[4] = {0.f, 0.f, 0.f, 0.f};
        for (int n0 = 0; n0 < 512; n0 += 32) {
            for (int i = tid; i < 2048; i += 256) {
                int nl = i >> 6, dd = i & 63;
                Pcs[nl][dd] = pbase[(n0 + nl) * 64 + dd];
            }
            __syncthreads();
            if (tid < 32) {
                int n = n0 + tid;
                float vv[16];
                float m = -1e30f;
                #pragma unroll
                for (int h = 0; h < 16; ++h) {
                    float val = blog[h][n];
                    if (fin) val += dbase[h * 512 + n];
                    vv[h] = val;
                    m = fmaxf(m, val);
                }
                float ssum = 0.f;
                #pragma unroll
                for (int h = 0; h < 16; ++h) { vv[h] = __expf(vv[h] - m); ssum += vv[h]; }
                float inv = 1.f / ssum;
                #pragma unroll
                for (int h = 0; h < 16; ++h) cs[h][tid] = vv[h] * inv;
            }
            __syncthreads();
            if (fin) {
                for (int i = tid; i < 512; i += 256) {
                    int h = i >> 5, nl = i & 31;
                    c_out[(bt * 16 + h) * 512 + n0 + nl] = cs[h][nl];
                }
            }
            for (int nl = 0; nl < 32; ++nl) {
                float p = Pcs[nl][d];
                #pragma unroll
                for (int j = 0; j < 4; ++j) acc[j] += cs[hq + 4 * j][nl] * p;
            }
            __syncthreads();
        }
        if (fin) {
            #pragma unroll
            for (int j = 0; j < 4; ++j)
                s_out[(bt * 16 + hq + 4 * j) * 64 + d] = acc[j];
        } else {
            #pragma unroll
            for (int j = 0; j < 4; ++j) {
                int h = hq + 4 * j;
                float s = sq1[h][d] * acc[j];
                float sq = warp_sum64(s * s);
                sv[h][d] = s * squash_factor(sq);
            }
            __syncthreads();
            // blog[h][n] += sum_d sv[h][d] * Pc[n][d]
            for (int n0 = 0; n0 < 512; n0 += 32) {
                for (int i = tid; i < 2048; i += 256) {
                    int nl = i >> 6, dd = i & 63;
                    Pcs[nl][dd] = pbase[(n0 + nl) * 64 + dd];
                }
                __syncthreads();
                #pragma unroll
                for (int rep = 0; rep < 2; ++rep) {
                    int o = tid + rep * 256;
                    int h = o >> 5, nl = o & 31;
                    float a2 = 0.f;
                    #pragma unroll
                    for (int dd = 0; dd < 64; ++dd) a2 += sv[h][dd] * Pcs[nl][dd];
                    blog[h][n0 + nl] += a2;
                }
                __syncthreads();
            }
        }
    }
}

// -------- Kernel 5: dyn + temporal hypergraph + v2 ---------------------
__global__ __launch_bounds__(256) void k_temporal(const float* __restrict__ time_eb,
        const float* __restrict__ t_adj, const float* __restrict__ s_out,
        float* __restrict__ dyn_out, float* __restrict__ v2) {
    int b = blockIdx.x;
    __shared__ float te[32];
    __shared__ float dyn[32][192];
    __shared__ float htem[32][64];
    int tid = threadIdx.x;
    if (tid < 32) te[tid] = time_eb[b * 32 + tid];
    __syncthreads();
    for (int i = tid; i < 32 * 192; i += 256) {
        int ht = i / 192, k = i % 192;
        float acc = 0.f;
        #pragma unroll
        for (int dd = 0; dd < 32; ++dd) acc += te[dd] * t_adj[(dd * 32 + ht) * 192 + k];
        dyn[ht][k] = acc;
        dyn_out[(b * 32 + ht) * 192 + k] = acc;
    }
    __syncthreads();
    const float* sb = s_out + b * TT_ * 64;
    {
        int d = tid & 63, htq = tid >> 6;
        float acc[8] = {};
        for (int k = 0; k < 192; ++k) {
            float hs = sb[k * 64 + d] + (float)(k / 16 + 1) * (1.f / 12.f);
            #pragma unroll
            for (int j = 0; j < 8; ++j) acc[j] += dyn[htq + 4 * j][k] * hs;
        }
        #pragma unroll
        for (int j = 0; j < 8; ++j) htem[htq + 4 * j][d] = lrelu(acc[j]);
    }
    __syncthreads();
    {
        int d = tid & 63, kq = tid >> 6;
        for (int j = 0; j < 48; ++j) {
            int k = kq + 4 * j;
            float acc = 0.f;
            #pragma unroll
            for (int ht = 0; ht < 32; ++ht) acc += dyn[ht][k] * htem[ht][d];
            float w = lrelu(acc) + sb[k * 64 + d];
            float sq = warp_sum64(w * w);
            v2[(b * 192 + k) * 64 + d] = w * squash_factor(sq);
        }
    }
}

// -------- Kernel 6: W_spatial, b_spatial -------------------------------
__global__ __launch_bounds__(256) void k_wsp(const float* __restrict__ ne,
        const float* __restrict__ wspa, const float* __restrict__ bspa,
        float* __restrict__ Wsp, float* __restrict__ bsp) {
    int n = blockIdx.x;
    __shared__ float nes[32];
    int tid = threadIdx.x;
    if (tid < 32) nes[tid] = ne[n * 32 + tid];
    __syncthreads();
    for (int i = tid; i < 4096; i += 256) {
        float acc = 0.f;
        #pragma unroll
        for (int dd = 0; dd < 32; ++dd) acc += nes[dd] * wspa[dd * 4096 + i];
        Wsp[n * 4096 + i] = acc;
    }
    if (tid < 64) {
        float acc = 0.f;
        #pragma unroll
        for (int dd = 0; dd < 32; ++dd) acc += nes[dd] * bspa[dd * 64 + tid];
        bsp[n * 64 + tid] = acc;
    }
}

// -------- Kernel 7: recon -> spatial proj -> lrelu(+x) -----------------
// grid = 512 n-blocks x 4 bt-groups (48 bt rows each)
__global__ __launch_bounds__(256) void k_final(const float* __restrict__ c_out,
        const float* __restrict__ v2, const float* __restrict__ Wsp,
        const float* __restrict__ bsp, const float* __restrict__ x,
        float* __restrict__ out) {
    int n = blockIdx.x & 511;
    int g = blockIdx.x >> 9;
    __shared__ float Ws[64][64];
    __shared__ float rec[4][64];
    int tid = threadIdx.x;
    for (int i = tid; i < 4096; i += 256) Ws[i >> 6][i & 63] = Wsp[n * 4096 + i];
    __syncthreads();
    int r = tid >> 6, o = tid & 63;
    float bias = bsp[n * 64 + o];
    for (int bt0 = g * 48; bt0 < g * 48 + 48; bt0 += 4) {
        int bt = bt0 + r;
        float ri = 0.f;
        #pragma unroll
        for (int h = 0; h < 16; ++h)
            ri += c_out[(bt * 16 + h) * 512 + n] * v2[(bt * 16 + h) * 64 + o];
        rec[r][o] = ri;
        __syncthreads();
        float acc = bias;
        #pragma unroll
        for (int i = 0; i < 64; ++i) acc += rec[r][i] * Ws[i][o];
        long idx = ((long)bt * 512 + n) * 64 + o;
        float v = acc + x[idx];
        out[idx] = lrelu(v);
        __syncthreads();
    }
}

extern "C" void kernel_launch(void* const* d_in, const int* in_sizes, int n_in,
                              void* d_out, int out_size, void* d_ws, size_t ws_size,
                              hipStream_t stream) {
    const float* x       = (const float*)d_in[0];
    const float* ne      = (const float*)d_in[1];
    const float* time_eb = (const float*)d_in[2];
    const float* teb     = (const float*)d_in[3];
    const float* Wp      = (const float*)d_in[4];
    const float* bp      = (const float*)d_in[5];
    const float* t_adj   = (const float*)d_in[6];
    const float* adj     = (const float*)d_in[7];
    const float* wspa    = (const float*)d_in[8];
    const float* bspa    = (const float*)d_in[9];

    float* out0    = (float*)d_out;                 // [B,T,N,D]   6,291,456
    float* c_out   = out0 + 6291456;                // [B,T,HS,N]  1,572,864
    float* dyn_out = out0 + 7864320;                // [B,HT,TT]      98,304

    float* ws    = (float*)d_ws;
    float* Pc    = ws;                // 6,291,456
    float* dadj  = ws + 6291456;      // 1,572,864
    float* sqt   = ws + 7864320;      //   196,608
    float* s_out = ws + 8060928;      //   196,608
    float* v2    = ws + 8257536;      //   196,608
    float* Wsp   = ws + 8454144;      // 2,097,152
    float* bsp   = ws + 10551296;     //    32,768

    k_pc<<<BT_ * N_ / 4, 256, 0, stream>>>(x, Wp, bp, Pc);
    k_dadj<<<BT_, 256, 0, stream>>>(teb, adj, dadj);
    k_wsp<<<N_, 256, 0, stream>>>(ne, wspa, bspa, Wsp, bsp);
    k_test1<<<BT_, 256, 0, stream>>>(dadj, Pc, sqt);
    k_route<<<BT_, 256, 0, stream>>>(dadj, Pc, sqt, c_out, s_out);
    k_temporal<<<B_, 256, 0, stream>>>(time_eb, t_adj, s_out, dyn_out, v2);
    k_final<<<N_ * 4, 256, 0, stream>>>(c_out, v2, Wsp, bsp, x, out0);
}

// Round 2
// 504.233 us; speedup vs baseline: 1.7788x; 1.7788x over previous
//
#include <hip/hip_runtime.h>
#include <hip/hip_bf16.h>

#define B_ 16
#define T_ 12
#define N_ 512
#define D_ 64
#define EDS_ 32
#define HS_ 16
#define HT_ 32
#define TT_ 192
#define BT_ (B_*T_)

typedef unsigned int uint32;
typedef unsigned short ushort16;

__device__ __forceinline__ float warp_sum64(float v) {
    #pragma unroll
    for (int off = 32; off > 0; off >>= 1) v += __shfl_xor(v, off);
    return v;
}

__device__ __forceinline__ float squash_factor(float sq) {
    return (sq / (1.f + sq)) / (sqrtf(sq) + 1e-8f);
}

__device__ __forceinline__ float lrelu(float v) {
    return (v >= 0.f) ? v : 0.01f * v;
}

__device__ __forceinline__ float bf2f(unsigned short u) {
    union { uint32 i; float f; } v; v.i = ((uint32)u) << 16; return v.f;
}

__device__ __forceinline__ unsigned short f2bf(float f) {
    __hip_bfloat16 b = __float2bfloat16(f);
    return *(unsigned short*)&b;
}

// -------- Kernel 1: Pc = squash(x @ W_p + b_p), output bf16 -------------
// grid = B*T*N/16, 256 threads; 16 rows per block.
__global__ __launch_bounds__(256) void k_pc(const float* __restrict__ x,
        const float* __restrict__ Wp, const float* __restrict__ bp,
        unsigned short* __restrict__ Pcg) {
    __shared__ float Ws[64][64];
    __shared__ float xs[16][64];
    int tid = threadIdx.x;
    for (int i = tid; i < 4096; i += 256) Ws[i >> 6][i & 63] = Wp[i];
    size_t row0 = (size_t)blockIdx.x * 16;
    for (int i = tid; i < 1024; i += 256) xs[i >> 6][i & 63] = x[row0 * 64 + i];
    __syncthreads();
    int r = tid >> 6, d = tid & 63;
    float bpd = bp[d];
    #pragma unroll
    for (int m = 0; m < 4; ++m) {
        int row = r + m * 4;
        float acc = bpd;
        #pragma unroll
        for (int k = 0; k < 64; ++k) acc += xs[row][k] * Ws[k][d];
        float sq = warp_sum64(acc * acc);
        Pcg[(row0 + row) * 64 + d] = f2bf(acc * squash_factor(sq));
    }
}

// -------- Kernel 2: dadj[b,t,h,n] = sum_d teb[b,t,d]*adj[d,h,n] --------
__global__ __launch_bounds__(256) void k_dadj(const float* __restrict__ teb,
        const float* __restrict__ adj, float* __restrict__ dadj) {
    int bt = blockIdx.x;
    __shared__ float ts[32];
    int tid = threadIdx.x;
    if (tid < 32) ts[tid] = teb[bt * 32 + tid];
    __syncthreads();
    for (int idx = tid; idx < HS_ * N_; idx += 256) {
        int h = idx >> 9, n = idx & 511;
        float acc = 0.f;
        #pragma unroll
        for (int dd = 0; dd < 32; ++dd) acc += ts[dd] * adj[(dd * 16 + h) * 512 + n];
        dadj[((size_t)bt * 16 + h) * 512 + n] = acc;
    }
}

// -------- Kernel 3: fused test1 + routing + final c/s ------------------
// grid = BT_, 1024 threads. Pc resident in LDS (bf16), blog in registers.
__global__ __launch_bounds__(1024, 4) void k_route2(
        const float* __restrict__ dadj, const unsigned short* __restrict__ Pcg,
        float* __restrict__ c_out, float* __restrict__ s_out) {
    __shared__ __align__(16) unsigned short Pcs[512][68]; // 69,632 B (pad 68 vs bank conflicts)
    __shared__ __align__(16) float cb[16][512];           // 32,768 B
    __shared__ __align__(16) float sred[4][16][64];       // 16,384 B (also aliased as vb)
    __shared__ __align__(16) float sq1b[16][64];          //  4,096 B
    const int bt = blockIdx.x;
    const int tid = threadIdx.x;

    // ---- stage Pc (bf16) into LDS, one dword (2 elems) per write ----
    {
        const uint32* src = (const uint32*)(Pcg + (size_t)bt * 32768);
        uint32* dst = (uint32*)&Pcs[0][0];
        #pragma unroll
        for (int i = tid; i < 16384; i += 1024) {
            int n = i >> 5, dp = i & 31;
            dst[n * 34 + dp] = src[i];
        }
    }

    // ---- per-thread roles ----
    const int na = tid >> 1;         // softmax/blog owner: n index
    const int g  = tid & 1;          // h-half (owns h = g*8 .. g*8+7)
    const int d  = tid & 63;         // s-pass lane
    const int h2 = tid >> 8;         // 0..3 -> h group base h2*4
    const int seg = (tid >> 6) & 3;  // n segment (128 each)
    const int h0 = h2 * 4;
    const int hr = tid >> 6;         // reduce role: h 0..15
    float* vb = &sred[0][0][0];      // v[16][64] aliases sred[0]

    float dv[8], blog[8];
    {
        const float* dbase = dadj + (size_t)bt * 8192;
        #pragma unroll
        for (int j = 0; j < 8; ++j) {
            dv[j] = dbase[(g * 8 + j) * 512 + na];
            blog[j] = 0.f;
        }
    }
    __syncthreads();

    // it=0: test1 (softmax(dadj) @ Pc -> squash -> sq1b)
    // it=1..3: routing iterations (c=softmax(blog); s; v; blog += v.Pc)
    // it=4: final c=softmax(blog+dadj) -> c_out; s -> s_out
    for (int it = 0; it < 5; ++it) {
        // ---- softmax over h (each thread owns 8 h for its n) ----
        {
            float vv[8];
            #pragma unroll
            for (int j = 0; j < 8; ++j)
                vv[j] = (it == 0) ? dv[j] : ((it == 4) ? blog[j] + dv[j] : blog[j]);
            float m = vv[0];
            #pragma unroll
            for (int j = 1; j < 8; ++j) m = fmaxf(m, vv[j]);
            m = fmaxf(m, __shfl_xor(m, 1));
            float ssum = 0.f;
            #pragma unroll
            for (int j = 0; j < 8; ++j) { vv[j] = __expf(vv[j] - m); ssum += vv[j]; }
            ssum += __shfl_xor(ssum, 1);
            float inv = 1.f / ssum;
            #pragma unroll
            for (int j = 0; j < 8; ++j) {
                float cv = vv[j] * inv;
                cb[g * 8 + j][na] = cv;
                if (it == 4) c_out[((size_t)bt * 16 + g * 8 + j) * 512 + na] = cv;
            }
        }
        __syncthreads();

        // ---- s-pass: s[h,d] = sum_n c[h,n]*Pc[n,d], 4 h per thread, n-seg split ----
        {
            float s4[4] = {0.f, 0.f, 0.f, 0.f};
            for (int nb = 0; nb < 32; ++nb) {
                int n0 = seg * 128 + nb * 4;
                float4 c0 = *(const float4*)&cb[h0 + 0][n0];
                float4 c1 = *(const float4*)&cb[h0 + 1][n0];
                float4 c2 = *(const float4*)&cb[h0 + 2][n0];
                float4 c3 = *(const float4*)&cb[h0 + 3][n0];
                #pragma unroll
                for (int q = 0; q < 4; ++q) {
                    float p = bf2f(Pcs[n0 + q][d]);
                    s4[0] = fmaf(((const float*)&c0)[q], p, s4[0]);
                    s4[1] = fmaf(((const float*)&c1)[q], p, s4[1]);
                    s4[2] = fmaf(((const float*)&c2)[q], p, s4[2]);
                    s4[3] = fmaf(((const float*)&c3)[q], p, s4[3]);
                }
            }
            #pragma unroll
            for (int j = 0; j < 4; ++j) sred[seg][h0 + j][d] = s4[j];
        }
        __syncthreads();

        // ---- cross-seg reduce + squash / output ----
        {
            float s = sred[0][hr][d] + sred[1][hr][d] + sred[2][hr][d] + sred[3][hr][d];
            if (it == 0) {
                float sq = warp_sum64(s * s);
                sq1b[hr][d] = s * squash_factor(sq);
            } else if (it < 4) {
                float st = sq1b[hr][d] * s;      // s of routing = sq1 * (c@Pc)
                float sq = warp_sum64(st * st);
                vb[hr * 64 + d] = st * squash_factor(sq);  // own slot of sred[0]
            } else {
                s_out[((size_t)bt * 16 + hr) * 64 + d] = s;
            }
        }
        __syncthreads();

        // ---- blog update: blog[h,n] += sum_d v[h,d]*Pc[n,d] ----
        if (it >= 1 && it <= 3) {
            float bacc[8] = {0.f,0.f,0.f,0.f,0.f,0.f,0.f,0.f};
            #pragma unroll
            for (int db = 0; db < 8; ++db) {
                uint2 pa = *(const uint2*)&Pcs[na][db * 8];
                uint2 pb = *(const uint2*)&Pcs[na][db * 8 + 4];
                float p0 = __uint_as_float(pa.x << 16);
                float p1 = __uint_as_float(pa.x & 0xffff0000u);
                float p2 = __uint_as_float(pa.y << 16);
                float p3 = __uint_as_float(pa.y & 0xffff0000u);
                float p4 = __uint_as_float(pb.x << 16);
                float p5 = __uint_as_float(pb.x & 0xffff0000u);
                float p6 = __uint_as_float(pb.y << 16);
                float p7 = __uint_as_float(pb.y & 0xffff0000u);
                #pragma unroll
                for (int j = 0; j < 8; ++j) {
                    const float* vrow = vb + (g * 8 + j) * 64 + db * 8;
                    float4 v0 = *(const float4*)vrow;
                    float4 v1 = *(const float4*)(vrow + 4);
                    bacc[j] += p0 * v0.x + p1 * v0.y + p2 * v0.z + p3 * v0.w
                             + p4 * v1.x + p5 * v1.y + p6 * v1.z + p7 * v1.w;
                }
            }
            #pragma unroll
            for (int j = 0; j < 8; ++j) blog[j] += bacc[j];
        }
    }
}

// -------- Kernel 5: dyn + temporal hypergraph + v2, 1024 threads -------
__global__ __launch_bounds__(1024) void k_temporal(const float* __restrict__ time_eb,
        const float* __restrict__ t_adj, const float* __restrict__ s_out,
        float* __restrict__ dyn_out, float* __restrict__ v2) {
    __shared__ float te[32];
    __shared__ float dyn[32][192];
    __shared__ float sblk[192][64];
    __shared__ float htem[32][64];
    __shared__ float mdot[32];
    int b = blockIdx.x, tid = threadIdx.x;
    if (tid < 32) te[tid] = time_eb[b * 32 + tid];
    const float* sb = s_out + (size_t)b * 12288;
    for (int i = tid; i < 12288; i += 1024) sblk[i >> 6][i & 63] = sb[i];
    __syncthreads();
    for (int i = tid; i < 6144; i += 1024) {
        int ht = i / 192, k = i - ht * 192;
        float acc = 0.f;
        #pragma unroll
        for (int dd = 0; dd < 32; ++dd) acc += te[dd] * t_adj[(dd * 32 + ht) * 192 + k];
        dyn[ht][k] = acc;
        dyn_out[((size_t)b * 32 + ht) * 192 + k] = acc;
    }
    __syncthreads();
    if (tid < 32) {
        float acc = 0.f;
        for (int k = 0; k < 192; ++k) acc += dyn[tid][k] * ((float)(k >> 4) + 1.f);
        mdot[tid] = acc * (1.f / 12.f);
    }
    __syncthreads();
    {
        int d = tid & 63, htb = tid >> 6;
        #pragma unroll
        for (int m = 0; m < 2; ++m) {
            int h = htb + m * 16;
            float acc = 0.f;
            for (int k = 0; k < 192; ++k) acc += dyn[h][k] * sblk[k][d];
            htem[h][d] = lrelu(acc + mdot[h]);
        }
    }
    __syncthreads();
    {
        int d = tid & 63, kq = tid >> 6;
        for (int k = kq; k < 192; k += 16) {
            float acc = 0.f;
            #pragma unroll
            for (int ht = 0; ht < 32; ++ht) acc += dyn[ht][k] * htem[ht][d];
            float w = lrelu(acc) + sblk[k][d];
            float sq = warp_sum64(w * w);
            v2[((size_t)b * 192 + k) * 64 + d] = w * squash_factor(sq);
        }
    }
}

// -------- Kernel 6: W_spatial, b_spatial -------------------------------
__global__ __launch_bounds__(256) void k_wsp(const float* __restrict__ ne,
        const float* __restrict__ wspa, const float* __restrict__ bspa,
        float* __restrict__ Wsp, float* __restrict__ bsp) {
    int n = blockIdx.x;
    __shared__ float nes[32];
    int tid = threadIdx.x;
    if (tid < 32) nes[tid] = ne[n * 32 + tid];
    __syncthreads();
    for (int i = tid; i < 4096; i += 256) {
        float acc = 0.f;
        #pragma unroll
        for (int dd = 0; dd < 32; ++dd) acc += nes[dd] * wspa[dd * 4096 + i];
        Wsp[(size_t)n * 4096 + i] = acc;
    }
    if (tid < 64) {
        float acc = 0.f;
        #pragma unroll
        for (int dd = 0; dd < 32; ++dd) acc += nes[dd] * bspa[dd * 64 + tid];
        bsp[n * 64 + tid] = acc;
    }
}

// -------- Kernel 7: recon -> spatial proj -> lrelu(+x) -----------------
// grid = 512 n-blocks x 16 bt-groups (12 bt rows each)
__global__ __launch_bounds__(256) void k_final(const float* __restrict__ c_out,
        const float* __restrict__ v2, const float* __restrict__ Wsp,
        const float* __restrict__ bsp, const float* __restrict__ x,
        float* __restrict__ out) {
    int n = blockIdx.x & 511;
    int gq = blockIdx.x >> 9;
    __shared__ float Ws[64][64];
    __shared__ float rec[4][64];
    int tid = threadIdx.x;
    for (int i = tid; i < 4096; i += 256) Ws[i >> 6][i & 63] = Wsp[(size_t)n * 4096 + i];
    __syncthreads();
    int r = tid >> 6, o = tid & 63;
    float bias = bsp[n * 64 + o];
    for (int bt0 = gq * 12; bt0 < gq * 12 + 12; bt0 += 4) {
        int bt = bt0 + r;
        float ri = 0.f;
        #pragma unroll
        for (int h = 0; h < 16; ++h)
            ri += c_out[((size_t)bt * 16 + h) * 512 + n] * v2[((size_t)bt * 16 + h) * 64 + o];
        rec[r][o] = ri;
        __syncthreads();
        float acc = bias;
        #pragma unroll
        for (int i = 0; i < 64; ++i) acc += rec[r][i] * Ws[i][o];
        size_t idx = ((size_t)bt * 512 + n) * 64 + o;
        out[idx] = lrelu(acc + x[idx]);
        __syncthreads();
    }
}

extern "C" void kernel_launch(void* const* d_in, const int* in_sizes, int n_in,
                              void* d_out, int out_size, void* d_ws, size_t ws_size,
                              hipStream_t stream) {
    const float* x       = (const float*)d_in[0];
    const float* ne      = (const float*)d_in[1];
    const float* time_eb = (const float*)d_in[2];
    const float* teb     = (const float*)d_in[3];
    const float* Wp      = (const float*)d_in[4];
    const float* bp      = (const float*)d_in[5];
    const float* t_adj   = (const float*)d_in[6];
    const float* adj     = (const float*)d_in[7];
    const float* wspa    = (const float*)d_in[8];
    const float* bspa    = (const float*)d_in[9];

    float* out0    = (float*)d_out;                 // [B,T,N,D]   6,291,456
    float* c_out   = out0 + 6291456;                // [B,T,HS,N]  1,572,864
    float* dyn_out = out0 + 7864320;                // [B,HT,TT]      98,304

    float* ws    = (float*)d_ws;
    float* dadj  = ws;                // 1,572,864 f32
    float* s_out = ws + 1572864;      //   196,608 f32
    float* v2    = ws + 1769472;      //   196,608 f32
    float* Wsp   = ws + 1966080;      // 2,097,152 f32
    float* bsp   = ws + 4063232;      //    32,768 f32
    unsigned short* Pcg = (unsigned short*)(ws + 4100096); // 6,291,456 bf16

    k_pc<<<BT_ * N_ / 16, 256, 0, stream>>>(x, Wp, bp, Pcg);
    k_dadj<<<BT_, 256, 0, stream>>>(teb, adj, dadj);
    k_wsp<<<N_, 256, 0, stream>>>(ne, wspa, bspa, Wsp, bsp);
    k_route2<<<BT_, 1024, 0, stream>>>(dadj, Pcg, c_out, s_out);
    k_temporal<<<B_, 1024, 0, stream>>>(time_eb, t_adj, s_out, dyn_out, v2);
    k_final<<<N_ * 16, 256, 0, stream>>>(c_out, v2, Wsp, bsp, x, out0);
}

// Round 4
// 382.121 us; speedup vs baseline: 2.3473x; 1.3196x over previous
//
#include <hip/hip_runtime.h>
#include <hip/hip_bf16.h>

#define B_ 16
#define T_ 12
#define N_ 512
#define D_ 64
#define EDS_ 32
#define HS_ 16
#define HT_ 32
#define TT_ 192
#define BT_ (B_*T_)

typedef unsigned int uint32;

__device__ __forceinline__ float warp_sum64(float v) {
    #pragma unroll
    for (int off = 32; off > 0; off >>= 1) v += __shfl_xor(v, off);
    return v;
}

__device__ __forceinline__ float squash_factor(float sq) {
    return (sq / (1.f + sq)) / (sqrtf(sq) + 1e-8f);
}

__device__ __forceinline__ float lrelu(float v) {
    return (v >= 0.f) ? v : 0.01f * v;
}

__device__ __forceinline__ float bf2f(unsigned short u) {
    union { uint32 i; float f; } v; v.i = ((uint32)u) << 16; return v.f;
}

__device__ __forceinline__ unsigned short f2bf(float f) {
    __hip_bfloat16 b = __float2bfloat16(f);
    return *(unsigned short*)&b;
}

// -------- Kernel 1: Pc = squash(x @ W_p + b_p), output bf16 -------------
// grid = B*T*N/32, 256 threads; 32 rows per block.
__global__ __launch_bounds__(256) void k_pc(const float* __restrict__ x,
        const float* __restrict__ Wp, const float* __restrict__ bp,
        unsigned short* __restrict__ Pcg) {
    __shared__ float Ws[64][64];
    __shared__ float xs[32][64];
    int tid = threadIdx.x;
    for (int i = tid; i < 1024; i += 256)
        ((float4*)&Ws[0][0])[i] = ((const float4*)Wp)[i];
    size_t row0 = (size_t)blockIdx.x * 32;
    const float4* xsrc = (const float4*)(x + row0 * 64);
    for (int i = tid; i < 512; i += 256)
        ((float4*)&xs[0][0])[i] = xsrc[i];
    __syncthreads();
    int r = tid >> 6, d = tid & 63;
    float bpd = bp[d];
    #pragma unroll
    for (int m = 0; m < 8; ++m) {
        int row = r + m * 4;
        float acc = bpd;
        #pragma unroll
        for (int k = 0; k < 64; ++k) acc += xs[row][k] * Ws[k][d];
        float sq = warp_sum64(acc * acc);
        Pcg[(row0 + row) * 64 + d] = f2bf(acc * squash_factor(sq));
    }
}

// -------- Kernel 2: dyn[b,ht,k] = sum_d time_eb[b,d]*t_adj[d,ht,k] -----
// grid = B_*24 blocks, 256 threads; 6144 outputs per b.
__global__ __launch_bounds__(256) void k_dyn(const float* __restrict__ time_eb,
        const float* __restrict__ t_adj, float* __restrict__ dyn_out) {
    int b = blockIdx.x / 24;
    int chunk = blockIdx.x - b * 24;
    __shared__ float te[32];
    int tid = threadIdx.x;
    if (tid < 32) te[tid] = time_eb[b * 32 + tid];
    __syncthreads();
    int i = chunk * 256 + tid;
    int ht = i / 192, k = i - ht * 192;
    float acc = 0.f;
    #pragma unroll
    for (int dd = 0; dd < 32; ++dd) acc += te[dd] * t_adj[(dd * 32 + ht) * 192 + k];
    dyn_out[(size_t)b * 6144 + i] = acc;
}

// -------- Kernel 3: fused dadj + test1 + routing + final c/s -----------
// grid = BT_, 1024 threads. Pc resident in LDS (bf16), blog in registers.
__global__ __launch_bounds__(1024, 4) void k_route2(
        const float* __restrict__ teb, const float* __restrict__ adj,
        const unsigned short* __restrict__ Pcg,
        float* __restrict__ c_out, float* __restrict__ s_out) {
    __shared__ __align__(16) unsigned short Pcs[512][68]; // 69,632 B
    __shared__ __align__(16) float cb[16][512];           // 32,768 B (also dadj scratch)
    __shared__ __align__(16) float sred[4][16][64];       // 16,384 B (also aliased as vb)
    __shared__ __align__(16) float sq1b[16][64];          //  4,096 B
    __shared__ float te[32];
    const int bt = blockIdx.x;
    const int tid = threadIdx.x;

    // ---- stage Pc (bf16) into LDS ----
    {
        const uint32* src = (const uint32*)(Pcg + (size_t)bt * 32768);
        uint32* dst = (uint32*)&Pcs[0][0];
        #pragma unroll
        for (int i = tid; i < 16384; i += 1024) {
            int n = i >> 5, dp = i & 31;
            dst[n * 34 + dp] = src[i];
        }
    }
    if (tid < 32) te[tid] = teb[bt * 32 + tid];
    __syncthreads();

    // ---- dadj[h][n] = sum_dd te[dd]*adj[dd][h][n] -> cb scratch ----
    #pragma unroll
    for (int grp = 0; grp < 2; ++grp) {
        int i = (tid + grp * 1024) * 4;
        int h = i >> 9, n0 = i & 511;
        float4 a4 = {0.f, 0.f, 0.f, 0.f};
        #pragma unroll
        for (int dd = 0; dd < 32; ++dd) {
            float4 a = *(const float4*)&adj[(size_t)(dd * 16 + h) * 512 + n0];
            float t = te[dd];
            a4.x = fmaf(t, a.x, a4.x);
            a4.y = fmaf(t, a.y, a4.y);
            a4.z = fmaf(t, a.z, a4.z);
            a4.w = fmaf(t, a.w, a4.w);
        }
        *(float4*)&cb[h][n0] = a4;
    }
    __syncthreads();

    // ---- per-thread roles ----
    const int na = tid >> 1;         // softmax/blog owner: n index
    const int g  = tid & 1;          // h-half (owns h = g*8 .. g*8+7)
    const int d  = tid & 63;         // s-pass lane
    const int h2 = tid >> 8;         // 0..3 -> h group base h2*4
    const int seg = (tid >> 6) & 3;  // n segment (128 each)
    const int h0 = h2 * 4;
    const int hr = tid >> 6;         // reduce role: h 0..15
    float* vb = &sred[0][0][0];      // v[16][64] aliases sred[0]

    float dv[8], blog[8];
    #pragma unroll
    for (int j = 0; j < 8; ++j) {
        dv[j] = cb[g * 8 + j][na];   // own slot: safe to overwrite below
        blog[j] = 0.f;
    }

    // it=0: test1 (softmax(dadj) @ Pc -> squash -> sq1b)
    // it=1..3: routing iterations (c=softmax(blog); s; v; blog += v.Pc)
    // it=4: final c=softmax(blog+dadj) -> c_out; s -> s_out
    for (int it = 0; it < 5; ++it) {
        // ---- softmax over h (each thread owns 8 h for its n) ----
        {
            float vv[8];
            #pragma unroll
            for (int j = 0; j < 8; ++j)
                vv[j] = (it == 0) ? dv[j] : ((it == 4) ? blog[j] + dv[j] : blog[j]);
            float m = vv[0];
            #pragma unroll
            for (int j = 1; j < 8; ++j) m = fmaxf(m, vv[j]);
            m = fmaxf(m, __shfl_xor(m, 1));
            float ssum = 0.f;
            #pragma unroll
            for (int j = 0; j < 8; ++j) { vv[j] = __expf(vv[j] - m); ssum += vv[j]; }
            ssum += __shfl_xor(ssum, 1);
            float inv = 1.f / ssum;
            #pragma unroll
            for (int j = 0; j < 8; ++j) {
                float cv = vv[j] * inv;
                cb[g * 8 + j][na] = cv;
                if (it == 4) c_out[((size_t)bt * 16 + g * 8 + j) * 512 + na] = cv;
            }
        }
        __syncthreads();

        // ---- s-pass: s[h,d] = sum_n c[h,n]*Pc[n,d], 4 h per thread ----
        {
            float s4[4] = {0.f, 0.f, 0.f, 0.f};
            for (int nb = 0; nb < 32; ++nb) {
                int n0 = seg * 128 + nb * 4;
                float4 c0 = *(const float4*)&cb[h0 + 0][n0];
                float4 c1 = *(const float4*)&cb[h0 + 1][n0];
                float4 c2 = *(const float4*)&cb[h0 + 2][n0];
                float4 c3 = *(const float4*)&cb[h0 + 3][n0];
                #pragma unroll
                for (int q = 0; q < 4; ++q) {
                    float p = bf2f(Pcs[n0 + q][d]);
                    s4[0] = fmaf(((const float*)&c0)[q], p, s4[0]);
                    s4[1] = fmaf(((const float*)&c1)[q], p, s4[1]);
                    s4[2] = fmaf(((const float*)&c2)[q], p, s4[2]);
                    s4[3] = fmaf(((const float*)&c3)[q], p, s4[3]);
                }
            }
            #pragma unroll
            for (int j = 0; j < 4; ++j) sred[seg][h0 + j][d] = s4[j];
        }
        __syncthreads();

        // ---- cross-seg reduce + squash / output ----
        {
            float s = sred[0][hr][d] + sred[1][hr][d] + sred[2][hr][d] + sred[3][hr][d];
            if (it == 0) {
                float sq = warp_sum64(s * s);
                sq1b[hr][d] = s * squash_factor(sq);
            } else if (it < 4) {
                float st = sq1b[hr][d] * s;
                float sq = warp_sum64(st * st);
                vb[hr * 64 + d] = st * squash_factor(sq);
            } else {
                s_out[((size_t)bt * 16 + hr) * 64 + d] = s;
            }
        }
        __syncthreads();

        // ---- blog update: blog[h,n] += sum_d v[h,d]*Pc[n,d] ----
        if (it >= 1 && it <= 3) {
            float bacc[8] = {0.f,0.f,0.f,0.f,0.f,0.f,0.f,0.f};
            #pragma unroll
            for (int db = 0; db < 8; ++db) {
                uint2 pa = *(const uint2*)&Pcs[na][db * 8];
                uint2 pb = *(const uint2*)&Pcs[na][db * 8 + 4];
                float p0 = __uint_as_float(pa.x << 16);
                float p1 = __uint_as_float(pa.x & 0xffff0000u);
                float p2 = __uint_as_float(pa.y << 16);
                float p3 = __uint_as_float(pa.y & 0xffff0000u);
                float p4 = __uint_as_float(pb.x << 16);
                float p5 = __uint_as_float(pb.x & 0xffff0000u);
                float p6 = __uint_as_float(pb.y << 16);
                float p7 = __uint_as_float(pb.y & 0xffff0000u);
                #pragma unroll
                for (int j = 0; j < 8; ++j) {
                    const float* vrow = vb + (g * 8 + j) * 64 + db * 8;
                    float4 v0 = *(const float4*)vrow;
                    float4 v1 = *(const float4*)(vrow + 4);
                    bacc[j] += p0 * v0.x + p1 * v0.y + p2 * v0.z + p3 * v0.w
                             + p4 * v1.x + p5 * v1.y + p6 * v1.z + p7 * v1.w;
                }
            }
            #pragma unroll
            for (int j = 0; j < 8; ++j) blog[j] += bacc[j];
        }
    }
}

// -------- Kernel 5: temporal hypergraph + v2 (dyn precomputed) ---------
__global__ __launch_bounds__(1024) void k_temporal(const float* __restrict__ dyn_in,
        const float* __restrict__ s_out, float* __restrict__ v2) {
    __shared__ float dyn[32][192];
    __shared__ float sblk[192][64];
    __shared__ float htem[32][64];
    __shared__ float mdot[32];
    int b = blockIdx.x, tid = threadIdx.x;
    const float4* dsrc = (const float4*)(dyn_in + (size_t)b * 6144);
    for (int i = tid; i < 1536; i += 1024) ((float4*)&dyn[0][0])[i] = dsrc[i];
    const float4* ssrc = (const float4*)(s_out + (size_t)b * 12288);
    for (int i = tid; i < 3072; i += 1024) ((float4*)&sblk[0][0])[i] = ssrc[i];
    __syncthreads();
    if (tid < 32) {
        float acc = 0.f;
        for (int k = 0; k < 192; ++k) acc += dyn[tid][k] * ((float)(k >> 4) + 1.f);
        mdot[tid] = acc * (1.f / 12.f);
    }
    __syncthreads();
    {
        int d = tid & 63, htb = tid >> 6;
        #pragma unroll
        for (int m = 0; m < 2; ++m) {
            int h = htb + m * 16;
            float acc = 0.f;
            for (int k = 0; k < 192; ++k) acc += dyn[h][k] * sblk[k][d];
            htem[h][d] = lrelu(acc + mdot[h]);
        }
    }
    __syncthreads();
    {
        int d = tid & 63, kq = tid >> 6;
        for (int k = kq; k < 192; k += 16) {
            float acc = 0.f;
            #pragma unroll
            for (int ht = 0; ht < 32; ++ht) acc += dyn[ht][k] * htem[ht][d];
            float w = lrelu(acc) + sblk[k][d];
            float sq = warp_sum64(w * w);
            v2[((size_t)b * 192 + k) * 64 + d] = w * squash_factor(sq);
        }
    }
}

// -------- Kernel 6: W_spatial, b_spatial -------------------------------
__global__ __launch_bounds__(256) void k_wsp(const float* __restrict__ ne,
        const float* __restrict__ wspa, const float* __restrict__ bspa,
        float* __restrict__ Wsp, float* __restrict__ bsp) {
    int n = blockIdx.x;
    __shared__ float nes[32];
    int tid = threadIdx.x;
    if (tid < 32) nes[tid] = ne[n * 32 + tid];
    __syncthreads();
    for (int i = tid; i < 4096; i += 256) {
        float acc = 0.f;
        #pragma unroll
        for (int dd = 0; dd < 32; ++dd) acc += nes[dd] * wspa[dd * 4096 + i];
        Wsp[(size_t)n * 4096 + i] = acc;
    }
    if (tid < 64) {
        float acc = 0.f;
        #pragma unroll
        for (int dd = 0; dd < 32; ++dd) acc += nes[dd] * bspa[dd * 64 + tid];
        bsp[n * 64 + tid] = acc;
    }
}

// -------- Kernel 7: recon -> spatial proj -> lrelu(+x) -----------------
// grid = 512 n-blocks x 16 bt-groups (12 bt rows each)
__global__ __launch_bounds__(256) void k_final(const float* __restrict__ c_out,
        const float* __restrict__ v2, const float* __restrict__ Wsp,
        const float* __restrict__ bsp, const float* __restrict__ x,
        float* __restrict__ out) {
    int n = blockIdx.x & 511;
    int gq = blockIdx.x >> 9;
    __shared__ float Ws[64][64];
    __shared__ float rec[4][64];
    int tid = threadIdx.x;
    const float4* wsrc = (const float4*)(Wsp + (size_t)n * 4096);
    for (int i = tid; i < 1024; i += 256) ((float4*)&Ws[0][0])[i] = wsrc[i];
    __syncthreads();
    int r = tid >> 6, o = tid & 63;
    float bias = bsp[n * 64 + o];
    for (int bt0 = gq * 12; bt0 < gq * 12 + 12; bt0 += 4) {
        int bt = bt0 + r;
        float ri = 0.f;
        #pragma unroll
        for (int h = 0; h < 16; ++h)
            ri += c_out[((size_t)bt * 16 + h) * 512 + n] * v2[((size_t)bt * 16 + h) * 64 + o];
        rec[r][o] = ri;
        __syncthreads();
        float acc = bias;
        #pragma unroll
        for (int i = 0; i < 64; ++i) acc += rec[r][i] * Ws[i][o];
        size_t idx = ((size_t)bt * 512 + n) * 64 + o;
        out[idx] = lrelu(acc + x[idx]);
        __syncthreads();
    }
}

extern "C" void kernel_launch(void* const* d_in, const int* in_sizes, int n_in,
                              void* d_out, int out_size, void* d_ws, size_t ws_size,
                              hipStream_t stream) {
    const float* x       = (const float*)d_in[0];
    const float* ne      = (const float*)d_in[1];
    const float* time_eb = (const float*)d_in[2];
    const float* teb     = (const float*)d_in[3];
    const float* Wp      = (const float*)d_in[4];
    const float* bp      = (const float*)d_in[5];
    const float* t_adj   = (const float*)d_in[6];
    const float* adj     = (const float*)d_in[7];
    const float* wspa    = (const float*)d_in[8];
    const float* bspa    = (const float*)d_in[9];

    float* out0    = (float*)d_out;                 // [B,T,N,D]   6,291,456
    float* c_out   = out0 + 6291456;                // [B,T,HS,N]  1,572,864
    float* dyn_out = out0 + 7864320;                // [B,HT,TT]      98,304

    float* ws    = (float*)d_ws;
    float* s_out = ws;                // 196,608 f32
    float* v2    = ws + 196608;       // 196,608 f32
    float* Wsp   = ws + 393216;       // 2,097,152 f32
    float* bsp   = ws + 2490368;      //    32,768 f32
    unsigned short* Pcg = (unsigned short*)(ws + 2523136); // 6,291,456 bf16

    k_pc<<<BT_ * N_ / 32, 256, 0, stream>>>(x, Wp, bp, Pcg);
    k_wsp<<<N_, 256, 0, stream>>>(ne, wspa, bspa, Wsp, bsp);
    k_dyn<<<B_ * 24, 256, 0, stream>>>(time_eb, t_adj, dyn_out);
    k_route2<<<BT_, 1024, 0, stream>>>(teb, adj, Pcg, c_out, s_out);
    k_temporal<<<B_, 1024, 0, stream>>>(dyn_out, s_out, v2);
    k_final<<<N_ * 16, 256, 0, stream>>>(c_out, v2, Wsp, bsp, x, out0);
}

// Round 10
// 342.545 us; speedup vs baseline: 2.6184x; 1.1155x over previous
//
#include <hip/hip_runtime.h>
#include <hip/hip_bf16.h>

#define B_ 16
#define T_ 12
#define N_ 512
#define D_ 64
#define EDS_ 32
#define HS_ 16
#define HT_ 32
#define TT_ 192
#define BT_ (B_*T_)

typedef unsigned int uint32;

__device__ __forceinline__ float warp_sum64(float v) {
    #pragma unroll
    for (int off = 32; off > 0; off >>= 1) v += __shfl_xor(v, off);
    return v;
}

__device__ __forceinline__ float squash_factor(float sq) {
    return (sq / (1.f + sq)) / (sqrtf(sq) + 1e-8f);
}

__device__ __forceinline__ float lrelu(float v) {
    return (v >= 0.f) ? v : 0.01f * v;
}

__device__ __forceinline__ float bflo(uint32 p) { return __uint_as_float(p << 16); }
__device__ __forceinline__ float bfhi(uint32 p) { return __uint_as_float(p & 0xffff0000u); }

__device__ __forceinline__ unsigned short f2bf(float f) {
    __hip_bfloat16 b = __float2bfloat16(f);
    return *(unsigned short*)&b;
}

// -------- Kernel 1: Pc = squash(x @ W_p + b_p), output bf16 TRANSPOSED --
// grid = BT_*16 blocks (32 n-rows each, single bt per block), 256 threads.
// Output layout: PcgT[bt][d][n]  (d=64, n=512)
__global__ __launch_bounds__(256) void k_pc(const float* __restrict__ x,
        const float* __restrict__ Wp, const float* __restrict__ bp,
        unsigned short* __restrict__ PcgT) {
    __shared__ float Ws[64][64];
    __shared__ float xs[32][64];
    __shared__ unsigned short tb[32][66];
    int tid = threadIdx.x;
    for (int i = tid; i < 1024; i += 256)
        ((float4*)&Ws[0][0])[i] = ((const float4*)Wp)[i];
    int bt = blockIdx.x >> 4;
    int n0 = (blockIdx.x & 15) * 32;
    size_t row0 = (size_t)bt * 512 + n0;
    const float4* xsrc = (const float4*)(x + row0 * 64);
    for (int i = tid; i < 512; i += 256)
        ((float4*)&xs[0][0])[i] = xsrc[i];
    __syncthreads();
    int r = tid >> 6, d = tid & 63;
    float bpd = bp[d];
    #pragma unroll
    for (int m = 0; m < 8; ++m) {
        int row = r + m * 4;
        float acc = bpd;
        #pragma unroll
        for (int k = 0; k < 64; ++k) acc += xs[row][k] * Ws[k][d];
        float sq = warp_sum64(acc * acc);
        tb[row][d] = f2bf(acc * squash_factor(sq));
    }
    __syncthreads();
    // pack & write transposed: PcgT[(bt*64+d)*512 + n0 + 2*np(+1)]
    for (int i = tid; i < 1024; i += 256) {
        int dd = i >> 4, np = i & 15;
        uint32 lo = tb[np * 2][dd], hi = tb[np * 2 + 1][dd];
        uint32 pack = lo | (hi << 16);
        *(uint32*)(PcgT + ((size_t)bt * 64 + dd) * 512 + n0 + np * 2) = pack;
    }
}

// -------- Kernel 2: dyn[b,ht,k] = sum_d time_eb[b,d]*t_adj[d,ht,k] -----
__global__ __launch_bounds__(256) void k_dyn(const float* __restrict__ time_eb,
        const float* __restrict__ t_adj, float* __restrict__ dyn_out) {
    int b = blockIdx.x / 24;
    int chunk = blockIdx.x - b * 24;
    __shared__ float te[32];
    int tid = threadIdx.x;
    if (tid < 32) te[tid] = time_eb[b * 32 + tid];
    __syncthreads();
    int i = chunk * 256 + tid;
    int ht = i / 192, k = i - ht * 192;
    float acc = 0.f;
    #pragma unroll
    for (int dd = 0; dd < 32; ++dd) acc += te[dd] * t_adj[(dd * 32 + ht) * 192 + k];
    dyn_out[(size_t)b * 6144 + i] = acc;
}

// -------- Kernel 3: fused dadj + test1 + routing + final c/s -----------
// grid = BT_, 1024 threads. PcT (bf16, transposed) + blog + c all in LDS.
__global__ __launch_bounds__(1024) void k_route2(
        const float* __restrict__ teb, const float* __restrict__ adj,
        const unsigned short* __restrict__ PcgT,
        float* __restrict__ c_out, float* __restrict__ s_out) {
    __shared__ __align__(16) unsigned short PcT[64][514]; // 65,792 B, row=257 dwords (odd)
    __shared__ __align__(16) float cb[16][512];           // 32,768 B (dadj scratch, then c)
    __shared__ __align__(16) float blg[16][512];          // 32,768 B
    __shared__ __align__(16) float sred[4][16][64];       // 16,384 B (sred[0] aliased as v)
    __shared__ __align__(16) float sq1b[16][64];          //  4,096 B
    __shared__ float te[32];
    const int bt = blockIdx.x;
    const int tid = threadIdx.x;

    // ---- stage PcT (linear copy; dst bank = (d + k) % 32, conflict-free) ----
    {
        const uint32* src = (const uint32*)(PcgT + (size_t)bt * 32768);
        uint32* dst = (uint32*)&PcT[0][0];
        #pragma unroll
        for (int i = tid; i < 16384; i += 1024) {
            int dd = i >> 8, k = i & 255;
            dst[dd * 257 + k] = src[i];
        }
    }
    if (tid < 32) te[tid] = teb[bt * 32 + tid];
    for (int i = tid; i < 8192; i += 1024) (&blg[0][0])[i] = 0.f;
    __syncthreads();

    // ---- dadj[h][n] = sum_dd te[dd]*adj[dd][h][n] -> cb scratch ----
    #pragma unroll
    for (int grp = 0; grp < 2; ++grp) {
        int i = (tid + grp * 1024) * 4;
        int h = i >> 9, n0 = i & 511;
        float4 a4 = {0.f, 0.f, 0.f, 0.f};
        #pragma unroll
        for (int dd = 0; dd < 32; ++dd) {
            float4 a = *(const float4*)&adj[(size_t)(dd * 16 + h) * 512 + n0];
            float t = te[dd];
            a4.x = fmaf(t, a.x, a4.x);
            a4.y = fmaf(t, a.y, a4.y);
            a4.z = fmaf(t, a.z, a4.z);
            a4.w = fmaf(t, a.w, a4.w);
        }
        *(float4*)&cb[h][n0] = a4;
    }
    __syncthreads();

    // ---- per-thread roles ----
    const int na = tid >> 1;         // softmax owner: n index
    const int g  = tid & 1;          // h-half (owns h = g*8 .. g*8+7)
    const int d  = tid & 63;         // s-pass lane / lane-in-wave
    const int seg = (tid >> 6) & 3;  // n segment (128 each)
    const int h0 = (tid >> 8) * 4;   // s-pass h group
    const int hr = tid >> 6;         // wave id == h for reduce & blog-update
    float* vb = &sred[0][0][0];      // v[16][64] aliases sred[0]

    float dv[8];
    #pragma unroll
    for (int j = 0; j < 8; ++j) dv[j] = cb[g * 8 + j][na]; // own slot

    // it=0: test1 (softmax(dadj) @ Pc -> squash -> sq1b)
    // it=1..3: routing (c=softmax(blog); s; v; blog += v.Pc)
    // it=4: final c=softmax(blog+dadj) -> c_out; s -> s_out
    for (int it = 0; it < 5; ++it) {
        // ---- A: softmax over h ----
        {
            float vv[8];
            #pragma unroll
            for (int j = 0; j < 8; ++j) {
                float bl = (it == 0) ? 0.f : blg[g * 8 + j][na];
                vv[j] = (it == 0) ? dv[j] : ((it == 4) ? bl + dv[j] : bl);
            }
            float m = vv[0];
            #pragma unroll
            for (int j = 1; j < 8; ++j) m = fmaxf(m, vv[j]);
            m = fmaxf(m, __shfl_xor(m, 1));
            float ssum = 0.f;
            #pragma unroll
            for (int j = 0; j < 8; ++j) { vv[j] = __expf(vv[j] - m); ssum += vv[j]; }
            ssum += __shfl_xor(ssum, 1);
            float inv = 1.f / ssum;
            #pragma unroll
            for (int j = 0; j < 8; ++j) {
                float cv = vv[j] * inv;
                cb[g * 8 + j][na] = cv;
                if (it == 4) c_out[((size_t)bt * 16 + g * 8 + j) * 512 + na] = cv;
            }
        }
        __syncthreads();

        // ---- B: s-pass  s[h,d] = sum_n c[h,n]*Pc[n,d] ----
        {
            float s4[4] = {0.f, 0.f, 0.f, 0.f};
            const uint32* prow = (const uint32*)&PcT[0][0] + d * 257 + seg * 64;
            #pragma unroll 4
            for (int np = 0; np < 64; np += 2) {
                uint32 pa = prow[np], pb = prow[np + 1];
                float p0 = bflo(pa), p1 = bfhi(pa), p2 = bflo(pb), p3 = bfhi(pb);
                int n0 = seg * 128 + np * 2;
                #pragma unroll
                for (int j = 0; j < 4; ++j) {
                    float4 c4 = *(const float4*)&cb[h0 + j][n0];  // wave-uniform broadcast
                    s4[j] = fmaf(c4.x, p0, fmaf(c4.y, p1, fmaf(c4.z, p2, fmaf(c4.w, p3, s4[j]))));
                }
            }
            #pragma unroll
            for (int j = 0; j < 4; ++j) sred[seg][h0 + j][d] = s4[j];
        }
        __syncthreads();

        // ---- C: cross-seg reduce + squash (v stays wave-local for D) ----
        {
            float s = sred[0][hr][d] + sred[1][hr][d] + sred[2][hr][d] + sred[3][hr][d];
            if (it == 0) {
                float sq = warp_sum64(s * s);
                sq1b[hr][d] = s * squash_factor(sq);
            } else if (it < 4) {
                float st = sq1b[hr][d] * s;
                float sq = warp_sum64(st * st);
                vb[hr * 64 + d] = st * squash_factor(sq);
            } else {
                s_out[((size_t)bt * 16 + hr) * 64 + d] = s;
            }
        }
        // no barrier: D's wave w reads only vb[w*64+..] written by its own wave in C

        // ---- D: blog[w][n] += sum_d v[w][d]*Pc[n,d], wave-per-h ----
        if (it >= 1 && it <= 3) {
            const int w = hr;
            const uint32* pc0 = (const uint32*)&PcT[0][0];
            #pragma unroll
            for (int c4i = 0; c4i < 4; ++c4i) {
                int npair = c4i * 64 + d;      // dword index in row (2 n's)
                float b0 = 0.f, b1 = 0.f;
                #pragma unroll 8
                for (int dd = 0; dd < 64; dd += 4) {
                    float4 v4 = *(const float4*)&vb[w * 64 + dd]; // wave-uniform
                    uint32 q0 = pc0[(dd + 0) * 257 + npair];
                    uint32 q1 = pc0[(dd + 1) * 257 + npair];
                    uint32 q2 = pc0[(dd + 2) * 257 + npair];
                    uint32 q3 = pc0[(dd + 3) * 257 + npair];
                    b0 = fmaf(v4.x, bflo(q0), b0); b1 = fmaf(v4.x, bfhi(q0), b1);
                    b0 = fmaf(v4.y, bflo(q1), b0); b1 = fmaf(v4.y, bfhi(q1), b1);
                    b0 = fmaf(v4.z, bflo(q2), b0); b1 = fmaf(v4.z, bfhi(q2), b1);
                    b0 = fmaf(v4.w, bflo(q3), b0); b1 = fmaf(v4.w, bfhi(q3), b1);
                }
                float2* bp2 = (float2*)&blg[w][0] + npair;
                float2 o = *bp2; o.x += b0; o.y += b1; *bp2 = o;
            }
        }
        __syncthreads();
    }
}

// -------- Kernel 5: temporal hypergraph + v2 (dyn precomputed) ---------
__global__ __launch_bounds__(1024) void k_temporal(const float* __restrict__ dyn_in,
        const float* __restrict__ s_out, float* __restrict__ v2) {
    __shared__ float dyn[32][192];
    __shared__ float sblk[192][64];
    __shared__ float htem[32][64];
    __shared__ float mdot[32];
    int b = blockIdx.x, tid = threadIdx.x;
    const float4* dsrc = (const float4*)(dyn_in + (size_t)b * 6144);
    for (int i = tid; i < 1536; i += 1024) ((float4*)&dyn[0][0])[i] = dsrc[i];
    const float4* ssrc = (const float4*)(s_out + (size_t)b * 12288);
    for (int i = tid; i < 3072; i += 1024) ((float4*)&sblk[0][0])[i] = ssrc[i];
    __syncthreads();
    if (tid < 32) {
        float acc = 0.f;
        for (int k = 0; k < 192; ++k) acc += dyn[tid][k] * ((float)(k >> 4) + 1.f);
        mdot[tid] = acc * (1.f / 12.f);
    }
    __syncthreads();
    {
        int d = tid & 63, htb = tid >> 6;
        #pragma unroll
        for (int m = 0; m < 2; ++m) {
            int h = htb + m * 16;
            float acc = 0.f;
            for (int k = 0; k < 192; ++k) acc += dyn[h][k] * sblk[k][d];
            htem[h][d] = lrelu(acc + mdot[h]);
        }
    }
    __syncthreads();
    {
        int d = tid & 63, kq = tid >> 6;
        for (int k = kq; k < 192; k += 16) {
            float acc = 0.f;
            #pragma unroll
            for (int ht = 0; ht < 32; ++ht) acc += dyn[ht][k] * htem[ht][d];
            float w = lrelu(acc) + sblk[k][d];
            float sq = warp_sum64(w * w);
            v2[((size_t)b * 192 + k) * 64 + d] = w * squash_factor(sq);
        }
    }
}

// -------- Kernel 6: W_spatial, b_spatial -------------------------------
__global__ __launch_bounds__(256) void k_wsp(const float* __restrict__ ne,
        const float* __restrict__ wspa, const float* __restrict__ bspa,
        float* __restrict__ Wsp, float* __restrict__ bsp) {
    int n = blockIdx.x;
    __shared__ float nes[32];
    int tid = threadIdx.x;
    if (tid < 32) nes[tid] = ne[n * 32 + tid];
    __syncthreads();
    for (int i = tid; i < 4096; i += 256) {
        float acc = 0.f;
        #pragma unroll
        for (int dd = 0; dd < 32; ++dd) acc += nes[dd] * wspa[dd * 4096 + i];
        Wsp[(size_t)n * 4096 + i] = acc;
    }
    if (tid < 64) {
        float acc = 0.f;
        #pragma unroll
        for (int dd = 0; dd < 32; ++dd) acc += nes[dd] * bspa[dd * 64 + tid];
        bsp[n * 64 + tid] = acc;
    }
}

// -------- Kernel 7: recon -> spatial proj -> lrelu(+x) -----------------
// grid = 512 n-blocks x 16 bt-groups (12 bt rows each)
__global__ __launch_bounds__(256) void k_final(const float* __restrict__ c_out,
        const float* __restrict__ v2, const float* __restrict__ Wsp,
        const float* __restrict__ bsp, const float* __restrict__ x,
        float* __restrict__ out) {
    int n = blockIdx.x & 511;
    int gq = blockIdx.x >> 9;
    __shared__ float Ws[64][64];
    __shared__ float rec[4][64];
    int tid = threadIdx.x;
    const float4* wsrc = (const float4*)(Wsp + (size_t)n * 4096);
    for (int i = tid; i < 1024; i += 256) ((float4*)&Ws[0][0])[i] = wsrc[i];
    __syncthreads();
    int r = tid >> 6, o = tid & 63;
    float bias = bsp[n * 64 + o];
    for (int bt0 = gq * 12; bt0 < gq * 12 + 12; bt0 += 4) {
        int bt = bt0 + r;
        float ri = 0.f;
        #pragma unroll
        for (int h = 0; h < 16; ++h)
            ri += c_out[((size_t)bt * 16 + h) * 512 + n] * v2[((size_t)bt * 16 + h) * 64 + o];
        rec[r][o] = ri;
        __syncthreads();
        float acc = bias;
        #pragma unroll
        for (int i = 0; i < 64; ++i) acc += rec[r][i] * Ws[i][o];
        size_t idx = ((size_t)bt * 512 + n) * 64 + o;
        out[idx] = lrelu(acc + x[idx]);
        __syncthreads();
    }
}

extern "C" void kernel_launch(void* const* d_in, const int* in_sizes, int n_in,
                              void* d_out, int out_size, void* d_ws, size_t ws_size,
                              hipStream_t stream) {
    const float* x       = (const float*)d_in[0];
    const float* ne      = (const float*)d_in[1];
    const float* time_eb = (const float*)d_in[2];
    const float* teb     = (const float*)d_in[3];
    const float* Wp      = (const float*)d_in[4];
    const float* bp      = (const float*)d_in[5];
    const float* t_adj   = (const float*)d_in[6];
    const float* adj     = (const float*)d_in[7];
    const float* wspa    = (const float*)d_in[8];
    const float* bspa    = (const float*)d_in[9];

    float* out0    = (float*)d_out;                 // [B,T,N,D]   6,291,456
    float* c_out   = out0 + 6291456;                // [B,T,HS,N]  1,572,864
    float* dyn_out = out0 + 7864320;                // [B,HT,TT]      98,304

    float* ws    = (float*)d_ws;
    float* s_out = ws;                // 196,608 f32
    float* v2    = ws + 196608;       // 196,608 f32
    float* Wsp   = ws + 393216;       // 2,097,152 f32
    float* bsp   = ws + 2490368;      //    32,768 f32
    unsigned short* PcgT = (unsigned short*)(ws + 2523136); // 6,291,456 bf16 (transposed per bt)

    k_pc<<<BT_ * 16, 256, 0, stream>>>(x, Wp, bp, PcgT);
    k_wsp<<<N_, 256, 0, stream>>>(ne, wspa, bspa, Wsp, bsp);
    k_dyn<<<B_ * 24, 256, 0, stream>>>(time_eb, t_adj, dyn_out);
    k_route2<<<BT_, 1024, 0, stream>>>(teb, adj, PcgT, c_out, s_out);
    k_temporal<<<B_, 1024, 0, stream>>>(dyn_out, s_out, v2);
    k_final<<<N_ * 16, 256, 0, stream>>>(c_out, v2, Wsp, bsp, x, out0);
}

// Round 13
// 294.726 us; speedup vs baseline: 3.0433x; 1.1623x over previous
//
#include <hip/hip_runtime.h>
#include <hip/hip_bf16.h>

#define B_ 16
#define T_ 12
#define N_ 512
#define D_ 64
#define EDS_ 32
#define HS_ 16
#define HT_ 32
#define TT_ 192
#define BT_ (B_*T_)

typedef unsigned int uint32;

__device__ __forceinline__ float warp_sum64(float v) {
    #pragma unroll
    for (int off = 32; off > 0; off >>= 1) v += __shfl_xor(v, off);
    return v;
}

__device__ __forceinline__ float squash_factor(float sq) {
    return (sq / (1.f + sq)) / (sqrtf(sq) + 1e-8f);
}

__device__ __forceinline__ float lrelu(float v) {
    return (v >= 0.f) ? v : 0.01f * v;
}

__device__ __forceinline__ float bflo(uint32 p) { return __uint_as_float(p << 16); }
__device__ __forceinline__ float bfhi(uint32 p) { return __uint_as_float(p & 0xffff0000u); }
__device__ __forceinline__ float bf2f(unsigned short u) {
    return __uint_as_float(((uint32)u) << 16);
}

__device__ __forceinline__ unsigned short f2bf(float f) {
    __hip_bfloat16 b = __float2bfloat16(f);
    return *(unsigned short*)&b;
}

// -------- Kernel 1: Pc = squash(x @ W_p + b_p), output bf16 TRANSPOSED --
// grid = BT_*16 blocks (32 n-rows each, single bt per block), 256 threads.
// Output layout: PcgT[bt][d][n]  (d=64, n=512)
__global__ __launch_bounds__(256) void k_pc(const float* __restrict__ x,
        const float* __restrict__ Wp, const float* __restrict__ bp,
        unsigned short* __restrict__ PcgT) {
    __shared__ float Ws[64][64];
    __shared__ float xs[32][64];
    __shared__ unsigned short tb[32][66];
    int tid = threadIdx.x;
    for (int i = tid; i < 1024; i += 256)
        ((float4*)&Ws[0][0])[i] = ((const float4*)Wp)[i];
    int bt = blockIdx.x >> 4;
    int n0 = (blockIdx.x & 15) * 32;
    size_t row0 = (size_t)bt * 512 + n0;
    const float4* xsrc = (const float4*)(x + row0 * 64);
    for (int i = tid; i < 512; i += 256)
        ((float4*)&xs[0][0])[i] = xsrc[i];
    __syncthreads();
    int r = tid >> 6, d = tid & 63;
    float bpd = bp[d];
    #pragma unroll
    for (int m = 0; m < 8; ++m) {
        int row = r + m * 4;
        float acc = bpd;
        #pragma unroll
        for (int k = 0; k < 64; ++k) acc += xs[row][k] * Ws[k][d];
        float sq = warp_sum64(acc * acc);
        tb[row][d] = f2bf(acc * squash_factor(sq));
    }
    __syncthreads();
    // pack & write transposed: PcgT[(bt*64+d)*512 + n0 + 2*np(+1)]
    for (int i = tid; i < 1024; i += 256) {
        int dd = i >> 4, np = i & 15;
        uint32 lo = tb[np * 2][dd], hi = tb[np * 2 + 1][dd];
        uint32 pack = lo | (hi << 16);
        *(uint32*)(PcgT + ((size_t)bt * 64 + dd) * 512 + n0 + np * 2) = pack;
    }
}

// -------- Kernel 2: dyn[b,ht,k] = sum_d time_eb[b,d]*t_adj[d,ht,k] -----
__global__ __launch_bounds__(256) void k_dyn(const float* __restrict__ time_eb,
        const float* __restrict__ t_adj, float* __restrict__ dyn_out) {
    int b = blockIdx.x / 24;
    int chunk = blockIdx.x - b * 24;
    __shared__ float te[32];
    int tid = threadIdx.x;
    if (tid < 32) te[tid] = time_eb[b * 32 + tid];
    __syncthreads();
    int i = chunk * 256 + tid;
    int ht = i / 192, k = i - ht * 192;
    float acc = 0.f;
    #pragma unroll
    for (int dd = 0; dd < 32; ++dd) acc += te[dd] * t_adj[(dd * 32 + ht) * 192 + k];
    dyn_out[(size_t)b * 6144 + i] = acc;
}

// -------- Kernel 3: fused dadj + test1 + routing + final c/s -----------
// grid = BT_, 1024 threads. PcT (bf16, transposed) + c in LDS; blog in regs.
__global__ __launch_bounds__(1024) void k_route2(
        const float* __restrict__ teb, const float* __restrict__ adj,
        const unsigned short* __restrict__ PcgT,
        float* __restrict__ c_out, float* __restrict__ s_out) {
    __shared__ __align__(16) unsigned short PcT[64][514]; // 65,792 B, row=257 dwords (odd)
    __shared__ __align__(16) float cb[16][512];           // 32,768 B (dadj scratch, then c)
    __shared__ __align__(16) float sred[4][16][64];       // 16,384 B (sred[0] aliased as v)
    __shared__ __align__(16) float sq1b[16][64];          //  4,096 B
    __shared__ float te[32];
    const int bt = blockIdx.x;
    const int tid = threadIdx.x;

    // ---- stage PcT (linear copy; dst bank = (d + k) % 32, conflict-free) ----
    {
        const uint32* src = (const uint32*)(PcgT + (size_t)bt * 32768);
        uint32* dst = (uint32*)&PcT[0][0];
        #pragma unroll
        for (int i = tid; i < 16384; i += 1024) {
            int dd = i >> 8, k = i & 255;
            dst[dd * 257 + k] = src[i];
        }
    }
    if (tid < 32) te[tid] = teb[bt * 32 + tid];
    __syncthreads();

    // ---- dadj[h][n] = sum_dd te[dd]*adj[dd][h][n] -> cb scratch ----
    #pragma unroll
    for (int grp = 0; grp < 2; ++grp) {
        int i = (tid + grp * 1024) * 4;
        int h = i >> 9, n0 = i & 511;
        float4 a4 = {0.f, 0.f, 0.f, 0.f};
        #pragma unroll
        for (int dd = 0; dd < 32; ++dd) {
            float4 a = *(const float4*)&adj[(size_t)(dd * 16 + h) * 512 + n0];
            float t = te[dd];
            a4.x = fmaf(t, a.x, a4.x);
            a4.y = fmaf(t, a.y, a4.y);
            a4.z = fmaf(t, a.z, a4.z);
            a4.w = fmaf(t, a.w, a4.w);
        }
        *(float4*)&cb[h][n0] = a4;
    }
    __syncthreads();

    // ---- per-thread roles ----
    const int na = tid >> 1;         // softmax/blog owner: n index
    const int g  = tid & 1;          // h-half (owns h = g*8 .. g*8+7)
    const int d  = tid & 63;         // s-pass lane / lane-in-wave
    const int seg = (tid >> 6) & 3;  // n segment (128 each)
    const int h0 = (tid >> 8) * 4;   // s-pass h group
    const int hr = tid >> 6;         // wave id == h for reduce
    float* vb = &sred[0][0][0];      // v[16][64] aliases sred[0]

    float dv[8], blog[8];
    #pragma unroll
    for (int j = 0; j < 8; ++j) {
        dv[j] = cb[g * 8 + j][na]; // own slot
        blog[j] = 0.f;
    }

    // it=0: test1 (softmax(dadj) @ Pc -> squash -> sq1b)
    // it=1..3: routing (c=softmax(blog); s; v; blog += v.Pc thread-local)
    // it=4: final c=softmax(blog+dadj) -> c_out; s -> s_out
    for (int it = 0; it < 5; ++it) {
        // ---- A: softmax over h (blog in registers) ----
        {
            float vv[8];
            #pragma unroll
            for (int j = 0; j < 8; ++j)
                vv[j] = (it == 0) ? dv[j] : ((it == 4) ? blog[j] + dv[j] : blog[j]);
            float m = vv[0];
            #pragma unroll
            for (int j = 1; j < 8; ++j) m = fmaxf(m, vv[j]);
            m = fmaxf(m, __shfl_xor(m, 1));
            float ssum = 0.f;
            #pragma unroll
            for (int j = 0; j < 8; ++j) { vv[j] = __expf(vv[j] - m); ssum += vv[j]; }
            ssum += __shfl_xor(ssum, 1);
            float inv = 1.f / ssum;
            #pragma unroll
            for (int j = 0; j < 8; ++j) {
                float cv = vv[j] * inv;
                cb[g * 8 + j][na] = cv;
                if (it == 4) c_out[((size_t)bt * 16 + g * 8 + j) * 512 + na] = cv;
            }
        }
        __syncthreads();

        // ---- B: s-pass  s[h,d] = sum_n c[h,n]*Pc[n,d] ----
        {
            float s4[4] = {0.f, 0.f, 0.f, 0.f};
            const uint32* prow = (const uint32*)&PcT[0][0] + d * 257 + seg * 64;
            #pragma unroll 4
            for (int np = 0; np < 64; np += 2) {
                uint32 pa = prow[np], pb = prow[np + 1];
                float p0 = bflo(pa), p1 = bfhi(pa), p2 = bflo(pb), p3 = bfhi(pb);
                int n0 = seg * 128 + np * 2;
                #pragma unroll
                for (int j = 0; j < 4; ++j) {
                    float4 c4 = *(const float4*)&cb[h0 + j][n0];  // wave-uniform broadcast
                    s4[j] = fmaf(c4.x, p0, fmaf(c4.y, p1, fmaf(c4.z, p2, fmaf(c4.w, p3, s4[j]))));
                }
            }
            #pragma unroll
            for (int j = 0; j < 4; ++j) sred[seg][h0 + j][d] = s4[j];
        }
        __syncthreads();

        // ---- C: cross-seg reduce + squash -> vb / outputs ----
        {
            float s = sred[0][hr][d] + sred[1][hr][d] + sred[2][hr][d] + sred[3][hr][d];
            if (it == 0) {
                float sq = warp_sum64(s * s);
                sq1b[hr][d] = s * squash_factor(sq);
            } else if (it < 4) {
                float st = sq1b[hr][d] * s;
                float sq = warp_sum64(st * st);
                vb[hr * 64 + d] = st * squash_factor(sq);
            } else {
                s_out[((size_t)bt * 16 + hr) * 64 + d] = s;
            }
        }
        __syncthreads();   // D' reads vb rows written by other waves

        // ---- D': blog[j] += sum_dd v[g*8+j][dd] * Pc[na][dd] (thread-local) ----
        // Pc column read: dword = dd*257 + (na>>1) -> 16 consecutive banks,
        // quad same-address broadcast. v read: 2 addrs/instr (g split), free.
        if (it >= 1 && it <= 3) {
            float bacc[8] = {0.f,0.f,0.f,0.f,0.f,0.f,0.f,0.f};
            #pragma unroll 4
            for (int dd = 0; dd < 64; dd += 4) {
                float p0 = bf2f(PcT[dd + 0][na]);
                float p1 = bf2f(PcT[dd + 1][na]);
                float p2 = bf2f(PcT[dd + 2][na]);
                float p3 = bf2f(PcT[dd + 3][na]);
                #pragma unroll
                for (int j = 0; j < 8; ++j) {
                    float4 v4 = *(const float4*)&vb[(g * 8 + j) * 64 + dd];
                    bacc[j] = fmaf(p0, v4.x, fmaf(p1, v4.y, fmaf(p2, v4.z, fmaf(p3, v4.w, bacc[j]))));
                }
            }
            #pragma unroll
            for (int j = 0; j < 8; ++j) blog[j] += bacc[j];
        }
        // no barrier needed: next A writes cb (disjoint from vb/PcT);
        // A->B barrier orders D' before B's sred overwrite.
    }
}

// -------- Kernel 5: temporal hypergraph + v2 (dyn precomputed) ---------
__global__ __launch_bounds__(1024) void k_temporal(const float* __restrict__ dyn_in,
        const float* __restrict__ s_out, float* __restrict__ v2) {
    __shared__ float dyn[32][192];
    __shared__ float sblk[192][64];
    __shared__ float htem[32][64];
    __shared__ float mdot[32];
    int b = blockIdx.x, tid = threadIdx.x;
    const float4* dsrc = (const float4*)(dyn_in + (size_t)b * 6144);
    for (int i = tid; i < 1536; i += 1024) ((float4*)&dyn[0][0])[i] = dsrc[i];
    const float4* ssrc = (const float4*)(s_out + (size_t)b * 12288);
    for (int i = tid; i < 3072; i += 1024) ((float4*)&sblk[0][0])[i] = ssrc[i];
    __syncthreads();
    if (tid < 32) {
        float acc = 0.f;
        for (int k = 0; k < 192; ++k) acc += dyn[tid][k] * ((float)(k >> 4) + 1.f);
        mdot[tid] = acc * (1.f / 12.f);
    }
    __syncthreads();
    {
        int d = tid & 63, htb = tid >> 6;
        #pragma unroll
        for (int m = 0; m < 2; ++m) {
            int h = htb + m * 16;
            float acc = 0.f;
            for (int k = 0; k < 192; ++k) acc += dyn[h][k] * sblk[k][d];
            htem[h][d] = lrelu(acc + mdot[h]);
        }
    }
    __syncthreads();
    {
        int d = tid & 63, kq = tid >> 6;
        for (int k = kq; k < 192; k += 16) {
            float acc = 0.f;
            #pragma unroll
            for (int ht = 0; ht < 32; ++ht) acc += dyn[ht][k] * htem[ht][d];
            float w = lrelu(acc) + sblk[k][d];
            float sq = warp_sum64(w * w);
            v2[((size_t)b * 192 + k) * 64 + d] = w * squash_factor(sq);
        }
    }
}

// -------- Kernel 6: W_spatial, b_spatial — register-tiled GEMM ---------
// grid = 64 n-groups × 4 i-groups = 256 blocks, 256 threads.
// Block: 8 n × 1024 i. Thread: float4 acc[8] (8 n × 4 i), 32 coalesced
// float4 wspa loads, 16 FMAs per LDS broadcast.
__global__ __launch_bounds__(256) void k_wsp(const float* __restrict__ ne,
        const float* __restrict__ wspa, const float* __restrict__ bspa,
        float* __restrict__ Wsp, float* __restrict__ bsp) {
    __shared__ float nes[8][32];
    int bid = blockIdx.x;
    int n0 = (bid >> 2) * 8;
    int i0 = (bid & 3) * 1024;
    int tid = threadIdx.x;
    nes[tid >> 5][tid & 31] = ne[(n0 + (tid >> 5)) * 32 + (tid & 31)];
    __syncthreads();
    int i = i0 + tid * 4;
    float4 acc[8];
    #pragma unroll
    for (int n = 0; n < 8; ++n) acc[n] = make_float4(0.f, 0.f, 0.f, 0.f);
    #pragma unroll 8
    for (int dd = 0; dd < 32; ++dd) {
        float4 w = *(const float4*)&wspa[dd * 4096 + i];
        #pragma unroll
        for (int n = 0; n < 8; ++n) {
            float e = nes[n][dd];
            acc[n].x = fmaf(e, w.x, acc[n].x);
            acc[n].y = fmaf(e, w.y, acc[n].y);
            acc[n].z = fmaf(e, w.z, acc[n].z);
            acc[n].w = fmaf(e, w.w, acc[n].w);
        }
    }
    #pragma unroll
    for (int n = 0; n < 8; ++n)
        *(float4*)&Wsp[(size_t)(n0 + n) * 4096 + i] = acc[n];
    // bsp[n][o] = sum_dd ne[n][dd]*bspa[dd][o] — handled by i-group 0 blocks
    if ((bid & 3) == 0) {
        int o = tid & 63;
        for (int nn = tid >> 6; nn < 8; nn += 4) {
            float acc2 = 0.f;
            #pragma unroll
            for (int dd = 0; dd < 32; ++dd) acc2 += nes[nn][dd] * bspa[dd * 64 + o];
            bsp[(n0 + nn) * 64 + o] = acc2;
        }
    }
}

// -------- Kernel 7: recon -> spatial proj -> lrelu(+x) -----------------
// grid = 512 n-blocks x 16 bt-groups (12 bt rows each)
__global__ __launch_bounds__(256) void k_final(const float* __restrict__ c_out,
        const float* __restrict__ v2, const float* __restrict__ Wsp,
        const float* __restrict__ bsp, const float* __restrict__ x,
        float* __restrict__ out) {
    int n = blockIdx.x & 511;
    int gq = blockIdx.x >> 9;
    __shared__ float Ws[64][64];
    __shared__ float rec[4][64];
    int tid = threadIdx.x;
    const float4* wsrc = (const float4*)(Wsp + (size_t)n * 4096);
    for (int i = tid; i < 1024; i += 256) ((float4*)&Ws[0][0])[i] = wsrc[i];
    __syncthreads();
    int r = tid >> 6, o = tid & 63;
    float bias = bsp[n * 64 + o];
    for (int bt0 = gq * 12; bt0 < gq * 12 + 12; bt0 += 4) {
        int bt = bt0 + r;
        float ri = 0.f;
        #pragma unroll
        for (int h = 0; h < 16; ++h)
            ri += c_out[((size_t)bt * 16 + h) * 512 + n] * v2[((size_t)bt * 16 + h) * 64 + o];
        rec[r][o] = ri;
        __syncthreads();
        float acc = bias;
        #pragma unroll
        for (int i = 0; i < 64; ++i) acc += rec[r][i] * Ws[i][o];
        size_t idx = ((size_t)bt * 512 + n) * 64 + o;
        out[idx] = lrelu(acc + x[idx]);
        __syncthreads();
    }
}

extern "C" void kernel_launch(void* const* d_in, const int* in_sizes, int n_in,
                              void* d_out, int out_size, void* d_ws, size_t ws_size,
                              hipStream_t stream) {
    const float* x       = (const float*)d_in[0];
    const float* ne      = (const float*)d_in[1];
    const float* time_eb = (const float*)d_in[2];
    const float* teb     = (const float*)d_in[3];
    const float* Wp      = (const float*)d_in[4];
    const float* bp      = (const float*)d_in[5];
    const float* t_adj   = (const float*)d_in[6];
    const float* adj     = (const float*)d_in[7];
    const float* wspa    = (const float*)d_in[8];
    const float* bspa    = (const float*)d_in[9];

    float* out0    = (float*)d_out;                 // [B,T,N,D]   6,291,456
    float* c_out   = out0 + 6291456;                // [B,T,HS,N]  1,572,864
    float* dyn_out = out0 + 7864320;                // [B,HT,TT]      98,304

    float* ws    = (float*)d_ws;
    float* s_out = ws;                // 196,608 f32
    float* v2    = ws + 196608;       // 196,608 f32
    float* Wsp   = ws + 393216;       // 2,097,152 f32
    float* bsp   = ws + 2490368;      //    32,768 f32
    unsigned short* PcgT = (unsigned short*)(ws + 2523136); // 6,291,456 bf16 (transposed per bt)

    k_pc<<<BT_ * 16, 256, 0, stream>>>(x, Wp, bp, PcgT);
    k_wsp<<<256, 256, 0, stream>>>(ne, wspa, bspa, Wsp, bsp);
    k_dyn<<<B_ * 24, 256, 0, stream>>>(time_eb, t_adj, dyn_out);
    k_route2<<<BT_, 1024, 0, stream>>>(teb, adj, PcgT, c_out, s_out);
    k_temporal<<<B_, 1024, 0, stream>>>(dyn_out, s_out, v2);
    k_final<<<N_ * 16, 256, 0, stream>>>(c_out, v2, Wsp, bsp, x, out0);
}